// Round 1
// 5626.493 us; speedup vs baseline: 1.2909x; 1.2909x over previous
//
#include <hip/hip_runtime.h>
#include <float.h>
#include <stdint.h>

#define QN 8
#define KN 1024
#define DN 64
// fp16-scan margin: est. worst-case scan-vs-exact deviation ~0.017 (16sigma pairwise headroom at 0.0625)
#define MARGIN 0.0625f

typedef float    f32x16 __attribute__((ext_vector_type(16)));
typedef _Float16 f16x8  __attribute__((ext_vector_type(8)));

union AB8 { uint4 v; uint32_t u[4]; f16x8 h; };

// ===================== FROZEN reference-emulation machinery =====================
// (validated: absmax = 0 vs harness np reference in prior session)
__device__ __forceinline__ float np_sumsq64(const float* a) {
    float p[DN];
    #pragma unroll
    for (int t = 0; t < DN; ++t) p[t] = __fmul_rn(a[t], a[t]);
    float l1[32];
    #pragma unroll
    for (int t = 0; t < 32; ++t) l1[t] = __fadd_rn(p[t], p[t + 32]);
    float l2[16];
    #pragma unroll
    for (int t = 0; t < 16; ++t) l2[t] = __fadd_rn(l1[t], l1[t + 16]);
    float l3[8];
    #pragma unroll
    for (int t = 0; t < 8; ++t) l3[t] = __fadd_rn(l2[t], l2[t + 8]);
    float l4[4];
    #pragma unroll
    for (int t = 0; t < 4; ++t) l4[t] = __fadd_rn(l3[t], l3[t + 4]);
    const float l5a = __fadd_rn(l4[0], l4[2]);
    const float l5b = __fadd_rn(l4[1], l4[3]);
    return __fadd_rn(l5a, l5b);
}

__device__ __forceinline__ float ref_res(const float* __restrict__ xrow,
                                         const float* __restrict__ cb,
                                         const int* code, int j, int d) {
    float qd = 0.f;
    #pragma unroll 1
    for (int l = 0; l < j; ++l)
        qd = __fadd_rn(qd, cb[((size_t)l * KN + code[l]) * DN + d]);
    return __fsub_rn(xrow[d], qd);
}

// Frozen 3-candidate exact rescore (identical ops to validated kernel; cn now from global)
__device__ __forceinline__ int rescore3(const float* __restrict__ xrow,
                                        const float* __restrict__ cb,
                                        const float* __restrict__ cnj,
                                        const int* code, int j,
                                        int i1, int i2, int i3) {
    float l1[32];
    #pragma unroll 1
    for (int t = 0; t < 32; ++t) {
        const float ra = ref_res(xrow, cb, code, j, t);
        const float rb = ref_res(xrow, cb, code, j, t + 32);
        l1[t] = __fadd_rn(__fmul_rn(ra, ra), __fmul_rn(rb, rb));
    }
    float l2[16];
    #pragma unroll
    for (int t = 0; t < 16; ++t) l2[t] = __fadd_rn(l1[t], l1[t + 16]);
    float l3[8];
    #pragma unroll
    for (int t = 0; t < 8; ++t) l3[t] = __fadd_rn(l2[t], l2[t + 8]);
    float l4[4];
    #pragma unroll
    for (int t = 0; t < 4; ++t) l4[t] = __fadd_rn(l3[t], l3[t + 4]);
    const float rr = __fadd_rn(__fadd_rn(l4[0], l4[2]), __fadd_rn(l4[1], l4[3]));

    const float* cbj = cb + (size_t)j * KN * DN;
    const float* c0p = cbj + (size_t)i1 * DN;
    const float* c1p = cbj + (size_t)i2 * DN;
    const float* c2p = cbj + (size_t)i3 * DN;
    float cr0 = 0.f, cr1 = 0.f, cr2 = 0.f;
    #pragma unroll 1
    for (int d = 0; d < DN; ++d) {
        const float rd = ref_res(xrow, cb, code, j, d);
        cr0 = __fmaf_rn(rd, c0p[d], cr0);
        cr1 = __fmaf_rn(rd, c1p[d], cr1);
        cr2 = __fmaf_rn(rd, c2p[d], cr2);
    }
    const float d2c0 = __fadd_rn(__fsub_rn(rr, __fmul_rn(2.0f, cr0)), cnj[i1]);
    const float d2c1 = __fadd_rn(__fsub_rn(rr, __fmul_rn(2.0f, cr1)), cnj[i2]);
    const float d2c2 = __fadd_rn(__fsub_rn(rr, __fmul_rn(2.0f, cr2)), cnj[i3]);

    float bd = d2c0; int bk = i1;
    if (d2c1 < bd || (d2c1 == bd && i2 < bk)) { bd = d2c1; bk = i2; }
    if (d2c2 < bd || (d2c2 == bd && i3 < bk)) { bd = d2c2; bk = i3; }
    return bk;
}

// Airtight safety net for 3-way near-ties: full reference-exact scan of all 1024
// codes (same per-k d2 formula as rescore3, strict < => first-min tie-break,
// exactly jnp.argmin semantics). Rare path; noinline to protect the hot loop.
__device__ __attribute__((noinline)) int full_exact(const float* __restrict__ xrow,
                                                    const float* __restrict__ cb,
                                                    const float* __restrict__ cnj,
                                                    const int* code, int j) {
    float rex[DN];
    #pragma unroll
    for (int d = 0; d < DN; ++d) rex[d] = ref_res(xrow, cb, code, j, d);
    float l1[32];
    #pragma unroll
    for (int t = 0; t < 32; ++t)
        l1[t] = __fadd_rn(__fmul_rn(rex[t], rex[t]), __fmul_rn(rex[t + 32], rex[t + 32]));
    float l2[16];
    #pragma unroll
    for (int t = 0; t < 16; ++t) l2[t] = __fadd_rn(l1[t], l1[t + 16]);
    float l3[8];
    #pragma unroll
    for (int t = 0; t < 8; ++t) l3[t] = __fadd_rn(l2[t], l2[t + 8]);
    float l4[4];
    #pragma unroll
    for (int t = 0; t < 4; ++t) l4[t] = __fadd_rn(l3[t], l3[t + 4]);
    const float rr = __fadd_rn(__fadd_rn(l4[0], l4[2]), __fadd_rn(l4[1], l4[3]));

    const float* cbj = cb + (size_t)j * KN * DN;
    float bd = FLT_MAX; int bk = 0;
    #pragma unroll 1
    for (int k = 0; k < KN; ++k) {
        const float* cp = cbj + (size_t)k * DN;
        float cr = 0.f;
        #pragma unroll
        for (int d = 0; d < DN; ++d) cr = __fmaf_rn(rex[d], cp[d], cr);
        const float d2 = __fadd_rn(__fsub_rn(rr, __fmul_rn(2.0f, cr)), cnj[k]);
        if (d2 < bd) { bd = d2; bk = k; }
    }
    return bk;
}
// ===============================================================================

__device__ __forceinline__ uint32_t pack2h(float a, float b) {
    const _Float16 ha = (_Float16)a, hb = (_Float16)b;   // RTN converts
    const uint16_t ua = __builtin_bit_cast(uint16_t, ha);
    const uint16_t ub = __builtin_bit_cast(uint16_t, hb);
    return (uint32_t)ua | ((uint32_t)ub << 16);
}

// ---------- Phase A: exact ||c||^2 + fp16(-2c) codebook in MFMA fragment order ----------
// Fragment-order layout (per 1KiB block = one (chunk,kstep)): for chunk c (32 codes),
// kstep kk (16 dims): slot s = (h<<5)|col holds 8 fp16: code c*32+col, dims kk*16+8h+e.
// A-operand read then is lane-linear (lane l reads slot l) -> conflict-free ds_read_b128.
__global__ __launch_bounds__(256) void rvq_prep_kernel(const float* __restrict__ cb,
                                                       uint32_t* __restrict__ apack,
                                                       float* __restrict__ cn) {
    const int cidx = (int)blockIdx.x * 256 + (int)threadIdx.x;
    if (cidx >= QN * KN) return;
    float row[DN];
    const float4* cp = (const float4*)(cb + (size_t)cidx * DN);
    #pragma unroll
    for (int d4 = 0; d4 < DN / 4; ++d4) {
        const float4 v = cp[d4];
        row[4*d4+0] = v.x; row[4*d4+1] = v.y; row[4*d4+2] = v.z; row[4*d4+3] = v.w;
    }
    cn[cidx] = np_sumsq64(row);                       // frozen exact ||c||^2

    const int j = cidx >> 10, local = cidx & 1023;
    const int c = local >> 5, col = local & 31;
    #pragma unroll
    for (int kk = 0; kk < 4; ++kk) {
        #pragma unroll
        for (int hh = 0; hh < 2; ++hh) {
            AB8 u;
            #pragma unroll
            for (int e = 0; e < 8; ++e)
                u.h[e] = (_Float16)(-2.0f * row[kk * 16 + hh * 8 + e]);  // -2x exact scale
            uint4* dst = (uint4*)(apack + (((size_t)(j * 32 + c) * 4 + kk) * 256
                                           + (((hh << 5) | col) << 2)));
            *dst = u.v;
        }
    }
}

// branchless top-3 insert (identical semantics to validated kernel's scan)
#define INS3(sv, ix, B1v, I1v, B2v, I2v, B3v, I3v) do {                      \
    const bool lt1 = (sv) < B1v, lt2 = (sv) < B2v, lt3 = (sv) < B3v;         \
    B3v = lt2 ? B2v : (lt3 ? (sv) : B3v); I3v = lt2 ? I2v : (lt3 ? (ix) : I3v); \
    B2v = lt1 ? B1v : (lt2 ? (sv) : B2v); I2v = lt1 ? I1v : (lt2 ? (ix) : I2v); \
    B1v = lt1 ? (sv) : B1v;               I1v = lt1 ? (ix) : I1v;            \
} while (0)

// ---------- Main: MFMA fp16 scan (codes = M rows, vectors = B cols), exact rescue ----------
// Wave handles 64 vectors (2 column groups sharing the A operand). Lane l owns vector
// wavebase+l (fp32 residual in regs). acc init = exact fp32 cn  =>  D = cn - 2 r.c.
// Triggers: b3-b1<MARGIN -> full_exact (covers any top-3 coverage doubt);
//           b2-b1<MARGIN -> frozen rescore3.  Else i1 is provably exact-best.
__global__ __launch_bounds__(256, 2) void rvq_encode_kernel(
    const float* __restrict__ x, const float* __restrict__ cb,
    const uint32_t* __restrict__ apack, const float* __restrict__ cnref,
    float* __restrict__ out_enc, float* __restrict__ out_q, int n) {
    __shared__ uint4  AL4[4096];   // 64 KiB: half-tile (16 chunks x 4 ksteps x 1KiB), fragment order
    __shared__ float4 CN4[128];    // 2 KiB: ||c||^2 for current half (fp32 exact)

    const int tid  = (int)threadIdx.x;
    const int lane = tid & 63;
    const int wid  = tid >> 6;
    const int h    = lane >> 5;          // K-half of the fragment this lane supplies

    const int iv  = (int)blockIdx.x * 256 + wid * 64 + lane;
    const int ivs = iv < n ? iv : (n - 1);
    const float* xrow = x + (size_t)ivs * DN;

    float r[DN];
    {
        const float4* xr = (const float4*)xrow;
        #pragma unroll
        for (int d4 = 0; d4 < DN / 4; ++d4) {
            const float4 v = xr[d4];
            r[4*d4+0] = v.x; r[4*d4+1] = v.y; r[4*d4+2] = v.z; r[4*d4+3] = v.w;
        }
    }

    int code[QN];

    #pragma unroll 1
    for (int j = 0; j < QN; ++j) {
        // ---- residual -> fp16 (RTN), packed pairs ----
        uint32_t rpk[32];
        #pragma unroll
        for (int m = 0; m < 32; ++m) rpk[m] = pack2h(r[2 * m], r[2 * m + 1]);

        // ---- build B fragments for both column groups via shfl_xor(32) ----
        // B[k'][col] with k' = 8h+e: group0 = vec (l&31), group1 = vec 32+(l&31).
        f16x8 bf0[4], bf1[4];
        #pragma unroll
        for (int kk = 0; kk < 4; ++kk) {
            AB8 t0, t1;
            #pragma unroll
            for (int q = 0; q < 4; ++q) {
                const uint32_t lo  = rpk[kk * 8 + q];        // dims kk*16 + 2q,2q+1
                const uint32_t hi  = rpk[kk * 8 + 4 + q];    // dims kk*16 + 8 + 2q,..
                const uint32_t plo = (uint32_t)__shfl_xor((int)lo, 32, 64);
                const uint32_t phi = (uint32_t)__shfl_xor((int)hi, 32, 64);
                t0.u[q] = h ? phi : lo;    // reader half h wants dims 8h.. of vec (l&31)
                t1.u[q] = h ? hi  : plo;   // ... of vec 32+(l&31)
            }
            bf0[kk] = t0.h; bf1[kk] = t1.h;
        }

        float b1g0 = FLT_MAX, b2g0 = FLT_MAX, b3g0 = FLT_MAX;
        float b1g1 = FLT_MAX, b2g1 = FLT_MAX, b3g1 = FLT_MAX;
        int   i1g0 = 0, i2g0 = 0, i3g0 = 0, i1g1 = 0, i2g1 = 0, i3g1 = 0;

        #pragma unroll 1
        for (int hf = 0; hf < 2; ++hf) {
            __syncthreads();   // previous tile fully consumed
            {   // stage 64 KiB A half-tile + 2 KiB cn (linear copies; tiny vs scan)
                const uint4* g4 = (const uint4*)(apack + ((size_t)(j * 32 + hf * 16) * 4) * 256);
                for (int t = tid; t < 4096; t += 256) AL4[t] = g4[t];
                const float4* c4 = (const float4*)(cnref + (size_t)j * KN + hf * 512);
                if (tid < 128) CN4[tid] = c4[tid];
            }
            __syncthreads();

            #pragma unroll 1
            for (int cl = 0; cl < 16; ++cl) {
                // acc init = exact fp32 cn for this lane's 16 code-rows
                f32x16 acc0;
                #pragma unroll
                for (int q = 0; q < 4; ++q) {
                    const float4 t = CN4[cl * 8 + q * 2 + h];
                    acc0[4*q+0] = t.x; acc0[4*q+1] = t.y; acc0[4*q+2] = t.z; acc0[4*q+3] = t.w;
                }
                f32x16 acc1 = acc0;

                #pragma unroll
                for (int kk = 0; kk < 4; ++kk) {
                    AB8 a; a.v = AL4[(cl * 4 + kk) * 64 + lane];   // conflict-free b128
                    acc0 = __builtin_amdgcn_mfma_f32_32x32x16_f16(a.h, bf0[kk], acc0, 0, 0, 0);
                    acc1 = __builtin_amdgcn_mfma_f32_32x32x16_f16(a.h, bf1[kk], acc1, 0, 0, 0);
                }

                // top-3 update; row(reg) = (reg&3) + 8*(reg>>2) + 4h  [C/D layout, m74/m101]
                const int ibase = (hf * 16 + cl) * 32 + 4 * h;
                #pragma unroll
                for (int q = 0; q < 16; ++q) {
                    const int ix = ibase + (q & 3) + 8 * (q >> 2);
                    { const float s = acc0[q]; INS3(s, ix, b1g0, i1g0, b2g0, i2g0, b3g0, i3g0); }
                    { const float s = acc1[q]; INS3(s, ix, b1g1, i1g1, b2g1, i2g1, b3g1, i3g1); }
                }
            }
        }

        // ---- merge the two K-half partial top-3 lists (lanes l <-> l^32) ----
        {
            const float pb1 = __shfl_xor(b1g0, 32, 64); const int pi1 = __shfl_xor(i1g0, 32, 64);
            const float pb2 = __shfl_xor(b2g0, 32, 64); const int pi2 = __shfl_xor(i2g0, 32, 64);
            const float pb3 = __shfl_xor(b3g0, 32, 64); const int pi3 = __shfl_xor(i3g0, 32, 64);
            INS3(pb1, pi1, b1g0, i1g0, b2g0, i2g0, b3g0, i3g0);
            INS3(pb2, pi2, b1g0, i1g0, b2g0, i2g0, b3g0, i3g0);
            INS3(pb3, pi3, b1g0, i1g0, b2g0, i2g0, b3g0, i3g0);
        }
        {
            const float pb1 = __shfl_xor(b1g1, 32, 64); const int pi1 = __shfl_xor(i1g1, 32, 64);
            const float pb2 = __shfl_xor(b2g1, 32, 64); const int pi2 = __shfl_xor(i2g1, 32, 64);
            const float pb3 = __shfl_xor(b3g1, 32, 64); const int pi3 = __shfl_xor(i3g1, 32, 64);
            INS3(pb1, pi1, b1g1, i1g1, b2g1, i2g1, b3g1, i3g1);
            INS3(pb2, pi2, b1g1, i1g1, b2g1, i2g1, b3g1, i3g1);
            INS3(pb3, pi3, b1g1, i1g1, b2g1, i2g1, b3g1, i3g1);
        }
        // lane l owns vector wavebase+l: group0 result for l<32, group1 for l>=32
        const float sb1 = h ? b1g1 : b1g0;
        const float sb2 = h ? b2g1 : b2g0;
        const float sb3 = h ? b3g1 : b3g0;
        const int   si1 = h ? i1g1 : i1g0;
        const int   si2 = h ? i2g1 : i2g0;
        const int   si3 = h ? i3g1 : i3g0;

        int chosen = si1;
        if (__builtin_expect(sb3 - sb1 < MARGIN, 0)) {
            chosen = full_exact(xrow, cb, cnref + (size_t)j * KN, code, j);
        } else if (__builtin_expect(sb2 - sb1 < MARGIN, 0)) {
            chosen = rescore3(xrow, cb, cnref + (size_t)j * KN, code, j, si1, si2, si3);
        }

        code[j] = chosen;
        if (iv < n) out_enc[(size_t)iv * QN + j] = (float)chosen;

        // drifted fp32 residual update (scan only; exactness via rebuild) — frozen
        const float4* cw = (const float4*)(cb + ((size_t)j * KN + chosen) * DN);
        #pragma unroll
        for (int d4 = 0; d4 < DN / 4; ++d4) {
            const float4 v = cw[d4];
            r[4*d4+0] -= v.x; r[4*d4+1] -= v.y; r[4*d4+2] -= v.z; r[4*d4+3] -= v.w;
        }
    }

    // ---- quantized output: reference-exact q rebuilt from codes (frozen) ----
    if (iv < n) {
        float4* qo = (float4*)(out_q + (size_t)iv * DN);
        #pragma unroll 1
        for (int d4 = 0; d4 < DN / 4; ++d4) {
            float q0 = 0.f, q1 = 0.f, q2 = 0.f, q3 = 0.f;
            #pragma unroll
            for (int l = 0; l < QN; ++l) {
                const float4 v = *(const float4*)(cb + ((size_t)l * KN + code[l]) * DN + 4 * d4);
                q0 = __fadd_rn(q0, v.x); q1 = __fadd_rn(q1, v.y);
                q2 = __fadd_rn(q2, v.z); q3 = __fadd_rn(q3, v.w);
            }
            float4 o; o.x = q0; o.y = q1; o.z = q2; o.w = q3;
            qo[d4] = o;
        }
    }
}

extern "C" void kernel_launch(void* const* d_in, const int* in_sizes, int n_in,
                              void* d_out, int out_size, void* d_ws, size_t ws_size,
                              hipStream_t stream) {
    const float* x   = (const float*)d_in[0];
    const float* cbp = (const float*)d_in[1];
    const int n = in_sizes[0] / DN;

    float* out_enc = (float*)d_out;                   // [N, Q]
    float* out_q   = (float*)d_out + (size_t)n * QN;  // [N, D]

    // workspace: 1 MiB fragment-order fp16(-2c) codebook + 32 KiB exact ||c||^2
    uint32_t* apack = (uint32_t*)d_ws;
    float*    cn    = (float*)((char*)d_ws + (size_t)QN * KN * DN * 2);

    rvq_prep_kernel<<<dim3((QN * KN + 255) / 256), dim3(256), 0, stream>>>(cbp, apack, cn);
    rvq_encode_kernel<<<dim3((n + 255) / 256), dim3(256), 0, stream>>>(
        x, cbp, apack, cn, out_enc, out_q, n);
}

// Round 2
// 3164.904 us; speedup vs baseline: 2.2950x; 1.7778x over previous
//
#include <hip/hip_runtime.h>
#include <float.h>
#include <stdint.h>

#define QN 8
#define KN 1024
#define DN 64
// split-fp16 scan: provable |s_scan - s_exact| <~ 3e-3 worst case; margin 5x that
#define MARGIN 1.5e-2f

typedef float    f32x16 __attribute__((ext_vector_type(16)));
typedef _Float16 f16x8  __attribute__((ext_vector_type(8)));

union AB8 { uint4 v; uint32_t u[4]; f16x8 h; };

struct CodeArr { int c[QN]; };

// ===================== FROZEN reference-emulation machinery =====================
__device__ __forceinline__ float np_sumsq64(const float* a) {
    float p[DN];
    #pragma unroll
    for (int t = 0; t < DN; ++t) p[t] = __fmul_rn(a[t], a[t]);
    float l1[32];
    #pragma unroll
    for (int t = 0; t < 32; ++t) l1[t] = __fadd_rn(p[t], p[t + 32]);
    float l2[16];
    #pragma unroll
    for (int t = 0; t < 16; ++t) l2[t] = __fadd_rn(l1[t], l1[t + 16]);
    float l3[8];
    #pragma unroll
    for (int t = 0; t < 8; ++t) l3[t] = __fadd_rn(l2[t], l2[t + 8]);
    float l4[4];
    #pragma unroll
    for (int t = 0; t < 4; ++t) l4[t] = __fadd_rn(l3[t], l3[t + 4]);
    const float l5a = __fadd_rn(l4[0], l4[2]);
    const float l5b = __fadd_rn(l4[1], l4[3]);
    return __fadd_rn(l5a, l5b);
}

// reference-exact residual: r_d = x_d - (((c0+c1)+c2)...) sequential fadd chain
__device__ __forceinline__ float ref_res(const float* __restrict__ xrow,
                                         const float* __restrict__ cb,
                                         const CodeArr& codes, int j, int d) {
    float qd = 0.f;
    #pragma unroll 1
    for (int l = 0; l < j; ++l)
        qd = __fadd_rn(qd, cb[((size_t)l * KN + codes.c[l]) * DN + d]);
    return __fsub_rn(xrow[d], qd);
}

// Frozen 2-candidate exact rescore (rescore3 minus candidate-3; retained ops identical).
// Valid because caller guarantees b3-b1 >= MARGIN here => only {i1,i2} can win.
__device__ __attribute__((noinline)) int rescore2(const float* __restrict__ xrow,
                                                  const float* __restrict__ cb,
                                                  const float* __restrict__ cnj,
                                                  CodeArr codes, int j,
                                                  int i1, int i2) {
    float l1[32];
    #pragma unroll 1
    for (int t = 0; t < 32; ++t) {
        const float ra = ref_res(xrow, cb, codes, j, t);
        const float rb = ref_res(xrow, cb, codes, j, t + 32);
        l1[t] = __fadd_rn(__fmul_rn(ra, ra), __fmul_rn(rb, rb));
    }
    float l2[16];
    #pragma unroll
    for (int t = 0; t < 16; ++t) l2[t] = __fadd_rn(l1[t], l1[t + 16]);
    float l3[8];
    #pragma unroll
    for (int t = 0; t < 8; ++t) l3[t] = __fadd_rn(l2[t], l2[t + 8]);
    float l4[4];
    #pragma unroll
    for (int t = 0; t < 4; ++t) l4[t] = __fadd_rn(l3[t], l3[t + 4]);
    const float rr = __fadd_rn(__fadd_rn(l4[0], l4[2]), __fadd_rn(l4[1], l4[3]));

    const float* cbj = cb + (size_t)j * KN * DN;
    const float* c0p = cbj + (size_t)i1 * DN;
    const float* c1p = cbj + (size_t)i2 * DN;
    float cr0 = 0.f, cr1 = 0.f;
    #pragma unroll 1
    for (int d = 0; d < DN; ++d) {
        const float rd = ref_res(xrow, cb, codes, j, d);
        cr0 = __fmaf_rn(rd, c0p[d], cr0);
        cr1 = __fmaf_rn(rd, c1p[d], cr1);
    }
    const float d2c0 = __fadd_rn(__fsub_rn(rr, __fmul_rn(2.0f, cr0)), cnj[i1]);
    const float d2c1 = __fadd_rn(__fsub_rn(rr, __fmul_rn(2.0f, cr1)), cnj[i2]);

    float bd = d2c0; int bk = i1;
    if (d2c1 < bd || (d2c1 == bd && i2 < bk)) { bd = d2c1; bk = i2; }
    return bk;
}

// Airtight safety net for 3-way near-ties: full reference-exact scan (frozen).
__device__ __attribute__((noinline)) int full_exact(const float* __restrict__ xrow,
                                                    const float* __restrict__ cb,
                                                    const float* __restrict__ cnj,
                                                    CodeArr codes, int j) {
    float rex[DN];
    #pragma unroll
    for (int d = 0; d < DN; ++d) rex[d] = ref_res(xrow, cb, codes, j, d);
    float l1[32];
    #pragma unroll
    for (int t = 0; t < 32; ++t)
        l1[t] = __fadd_rn(__fmul_rn(rex[t], rex[t]), __fmul_rn(rex[t + 32], rex[t + 32]));
    float l2[16];
    #pragma unroll
    for (int t = 0; t < 16; ++t) l2[t] = __fadd_rn(l1[t], l1[t + 16]);
    float l3[8];
    #pragma unroll
    for (int t = 0; t < 8; ++t) l3[t] = __fadd_rn(l2[t], l2[t + 8]);
    float l4[4];
    #pragma unroll
    for (int t = 0; t < 4; ++t) l4[t] = __fadd_rn(l3[t], l3[t + 4]);
    const float rr = __fadd_rn(__fadd_rn(l4[0], l4[2]), __fadd_rn(l4[1], l4[3]));

    const float* cbj = cb + (size_t)j * KN * DN;
    float bd = FLT_MAX; int bk = 0;
    #pragma unroll 1
    for (int k = 0; k < KN; ++k) {
        const float* cp = cbj + (size_t)k * DN;
        float cr = 0.f;
        #pragma unroll
        for (int d = 0; d < DN; ++d) cr = __fmaf_rn(rex[d], cp[d], cr);
        const float d2 = __fadd_rn(__fsub_rn(rr, __fmul_rn(2.0f, cr)), cnj[k]);
        if (d2 < bd) { bd = d2; bk = k; }
    }
    return bk;
}
// ===============================================================================

// ---------- Phase A: exact ||c||^2 + split-fp16(-2c) codebook in fragment order ----------
// Layout identical to validated round-1 apack; apackL holds fp16(-2c - fp32(apackH)).
__global__ __launch_bounds__(256) void rvq_prep_kernel(const float* __restrict__ cb,
                                                       uint32_t* __restrict__ apackH,
                                                       uint32_t* __restrict__ apackL,
                                                       float* __restrict__ cn) {
    const int cidx = (int)blockIdx.x * 256 + (int)threadIdx.x;
    if (cidx >= QN * KN) return;
    float row[DN];
    const float4* cp = (const float4*)(cb + (size_t)cidx * DN);
    #pragma unroll
    for (int d4 = 0; d4 < DN / 4; ++d4) {
        const float4 v = cp[d4];
        row[4*d4+0] = v.x; row[4*d4+1] = v.y; row[4*d4+2] = v.z; row[4*d4+3] = v.w;
    }
    cn[cidx] = np_sumsq64(row);                       // frozen exact ||c||^2

    const int j = cidx >> 10, local = cidx & 1023;
    const int c = local >> 5, col = local & 31;
    #pragma unroll
    for (int kk = 0; kk < 4; ++kk) {
        #pragma unroll
        for (int hh = 0; hh < 2; ++hh) {
            AB8 uh, ul;
            #pragma unroll
            for (int e = 0; e < 8; ++e) {
                const float v = -2.0f * row[kk * 16 + hh * 8 + e];   // exact (x2, negate)
                const _Float16 hi = (_Float16)v;
                const float hr = (float)hi;
                const _Float16 lo = (_Float16)__fsub_rn(v, hr);
                uh.h[e] = hi; ul.h[e] = lo;
            }
            const size_t off = (((size_t)(j * 32 + c) * 4 + kk) * 256
                                + (((hh << 5) | col) << 2));
            *(uint4*)(apackH + off) = uh.v;
            *(uint4*)(apackL + off) = ul.v;
        }
    }
}

// branchless top-3 insert, i3 dropped (b3 kept for the full_exact trigger)
#define INS3(sv, ix, B1v, I1v, B2v, I2v, B3v) do {                           \
    const bool lt1 = (sv) < B1v, lt2 = (sv) < B2v, lt3 = (sv) < B3v;         \
    B3v = lt2 ? B2v : (lt3 ? (sv) : B3v);                                     \
    B2v = lt1 ? B1v : (lt2 ? (sv) : B2v); I2v = lt1 ? I1v : (lt2 ? (ix) : I2v); \
    B1v = lt1 ? (sv) : B1v;               I1v = lt1 ? (ix) : I1v;            \
} while (0)

// ---------- Main: barrier-free split-fp16 MFMA scan, L2-direct fragments ----------
// 1-wave blocks; wave covers 64 vectors (2 column groups). Lane l owns vector
// blockbase+l. acc init = exact fp32 cn => s = cn - 2 r.c with r the EXACT residual
// (rebuilt per stage via the frozen chain; stage loop fully unrolled so codes.c[]
// stays register-resident). Rescues: b3-b1<M -> full_exact; b2-b1<M -> rescore2.
__global__ __launch_bounds__(64, 3) void rvq_encode_kernel(
    const float* __restrict__ x, const float* __restrict__ cb,
    const uint32_t* __restrict__ apackH, const uint32_t* __restrict__ apackL,
    const float* __restrict__ cnref,
    float* __restrict__ out_enc, float* __restrict__ out_q, int n) {
    const int lane = (int)threadIdx.x;
    const int h    = lane >> 5;
    const int iv   = (int)blockIdx.x * 64 + lane;
    const int ivs  = iv < n ? iv : (n - 1);
    const float* xrow = x + (size_t)ivs * DN;

    CodeArr codes;

    #pragma unroll
    for (int j = 0; j < QN; ++j) {
        // ---- exact residual rebuild + split-fp16 pack + B-fragment build ----
        f16x8 bh0[4], bh1[4], bl0[4], bl1[4];
        #pragma unroll
        for (int kk = 0; kk < 4; ++kk) {
            float rex[16];
            #pragma unroll
            for (int d4 = 0; d4 < 4; ++d4) {
                const float4 xv = *(const float4*)(xrow + kk * 16 + 4 * d4);
                float q0 = 0.f, q1 = 0.f, q2 = 0.f, q3 = 0.f;
                #pragma unroll
                for (int l = 0; l < j; ++l) {     // j compile-time: fully unrolled
                    const float4 cv = *(const float4*)(
                        cb + ((size_t)l * KN + codes.c[l]) * DN + kk * 16 + 4 * d4);
                    q0 = __fadd_rn(q0, cv.x); q1 = __fadd_rn(q1, cv.y);
                    q2 = __fadd_rn(q2, cv.z); q3 = __fadd_rn(q3, cv.w);
                }
                rex[4*d4+0] = __fsub_rn(xv.x, q0); rex[4*d4+1] = __fsub_rn(xv.y, q1);
                rex[4*d4+2] = __fsub_rn(xv.z, q2); rex[4*d4+3] = __fsub_rn(xv.w, q3);
            }
            uint32_t rh[8], rl[8];
            #pragma unroll
            for (int m = 0; m < 8; ++m) {
                const float a = rex[2*m], b = rex[2*m+1];
                const _Float16 ah16 = (_Float16)a; const float ar = (float)ah16;
                const _Float16 al16 = (_Float16)__fsub_rn(a, ar);
                const _Float16 bh16 = (_Float16)b; const float br = (float)bh16;
                const _Float16 bl16 = (_Float16)__fsub_rn(b, br);
                rh[m] = (uint32_t)__builtin_bit_cast(uint16_t, ah16)
                      | ((uint32_t)__builtin_bit_cast(uint16_t, bh16) << 16);
                rl[m] = (uint32_t)__builtin_bit_cast(uint16_t, al16)
                      | ((uint32_t)__builtin_bit_cast(uint16_t, bl16) << 16);
            }
            AB8 t0, t1, s0, s1;
            #pragma unroll
            for (int q = 0; q < 4; ++q) {
                const uint32_t lo  = rh[q],     hi  = rh[4 + q];
                const uint32_t plo = (uint32_t)__shfl_xor((int)lo, 32, 64);
                const uint32_t phi = (uint32_t)__shfl_xor((int)hi, 32, 64);
                t0.u[q] = h ? phi : lo;
                t1.u[q] = h ? hi  : plo;
                const uint32_t llo = rl[q],     lhi = rl[4 + q];
                const uint32_t qlo = (uint32_t)__shfl_xor((int)llo, 32, 64);
                const uint32_t qhi = (uint32_t)__shfl_xor((int)lhi, 32, 64);
                s0.u[q] = h ? qhi : llo;
                s1.u[q] = h ? lhi : qlo;
            }
            bh0[kk] = t0.h; bh1[kk] = t1.h; bl0[kk] = s0.h; bl1[kk] = s1.h;
        }

        float b1g0 = FLT_MAX, b2g0 = FLT_MAX, b3g0 = FLT_MAX; int i1g0 = 0, i2g0 = 0;
        float b1g1 = FLT_MAX, b2g1 = FLT_MAX, b3g1 = FLT_MAX; int i1g1 = 0, i2g1 = 0;

        const uint32_t* aH  = apackH + (size_t)j * 32768;
        const uint32_t* aL  = apackL + (size_t)j * 32768;
        const float*    cnj = cnref + (size_t)j * KN;

        #pragma unroll 1
        for (int ch = 0; ch < 32; ++ch) {
            f32x16 acc0;
            #pragma unroll
            for (int q = 0; q < 4; ++q) {
                const float4 t = *(const float4*)(cnj + ch * 32 + q * 8 + h * 4);
                acc0[4*q+0] = t.x; acc0[4*q+1] = t.y; acc0[4*q+2] = t.z; acc0[4*q+3] = t.w;
            }
            f32x16 acc1 = acc0;
            #pragma unroll
            for (int kk = 0; kk < 4; ++kk) {
                AB8 ah_, al_;
                ah_.v = *(const uint4*)(aH + (size_t)(ch * 4 + kk) * 256 + lane * 4);
                al_.v = *(const uint4*)(aL + (size_t)(ch * 4 + kk) * 256 + lane * 4);
                acc0 = __builtin_amdgcn_mfma_f32_32x32x16_f16(ah_.h, bh0[kk], acc0, 0, 0, 0);
                acc1 = __builtin_amdgcn_mfma_f32_32x32x16_f16(ah_.h, bh1[kk], acc1, 0, 0, 0);
                acc0 = __builtin_amdgcn_mfma_f32_32x32x16_f16(al_.h, bh0[kk], acc0, 0, 0, 0);
                acc1 = __builtin_amdgcn_mfma_f32_32x32x16_f16(al_.h, bh1[kk], acc1, 0, 0, 0);
                acc0 = __builtin_amdgcn_mfma_f32_32x32x16_f16(ah_.h, bl0[kk], acc0, 0, 0, 0);
                acc1 = __builtin_amdgcn_mfma_f32_32x32x16_f16(ah_.h, bl1[kk], acc1, 0, 0, 0);
            }
            const int ibase = ch * 32 + 4 * h;
            #pragma unroll
            for (int q = 0; q < 16; ++q) {
                const int ix = ibase + (q & 3) + 8 * (q >> 2);
                { const float s = acc0[q]; INS3(s, ix, b1g0, i1g0, b2g0, i2g0, b3g0); }
                { const float s = acc1[q]; INS3(s, ix, b1g1, i1g1, b2g1, i2g1, b3g1); }
            }
        }

        // ---- merge K-half partial lists (lanes l <-> l^32); pb3 dummy-ix safe ----
        {
            const float pb1 = __shfl_xor(b1g0, 32, 64); const int pi1 = __shfl_xor(i1g0, 32, 64);
            const float pb2 = __shfl_xor(b2g0, 32, 64); const int pi2 = __shfl_xor(i2g0, 32, 64);
            const float pb3 = __shfl_xor(b3g0, 32, 64);
            INS3(pb1, pi1, b1g0, i1g0, b2g0, i2g0, b3g0);
            INS3(pb2, pi2, b1g0, i1g0, b2g0, i2g0, b3g0);
            INS3(pb3, 0,   b1g0, i1g0, b2g0, i2g0, b3g0);
        }
        {
            const float pb1 = __shfl_xor(b1g1, 32, 64); const int pi1 = __shfl_xor(i1g1, 32, 64);
            const float pb2 = __shfl_xor(b2g1, 32, 64); const int pi2 = __shfl_xor(i2g1, 32, 64);
            const float pb3 = __shfl_xor(b3g1, 32, 64);
            INS3(pb1, pi1, b1g1, i1g1, b2g1, i2g1, b3g1);
            INS3(pb2, pi2, b1g1, i1g1, b2g1, i2g1, b3g1);
            INS3(pb3, 0,   b1g1, i1g1, b2g1, i2g1, b3g1);
        }
        const float sb1 = h ? b1g1 : b1g0;
        const float sb2 = h ? b2g1 : b2g0;
        const float sb3 = h ? b3g1 : b3g0;
        const int   si1 = h ? i1g1 : i1g0;
        const int   si2 = h ? i2g1 : i2g0;

        int chosen = si1;
        if (__builtin_expect(sb2 - sb1 < MARGIN, 0)) {
            if (sb3 - sb1 < MARGIN)
                chosen = full_exact(xrow, cb, cnj, codes, j);
            else
                chosen = rescore2(xrow, cb, cnj, codes, j, si1, si2);
        }
        codes.c[j] = chosen;
    }

    if (iv < n) {
        // ---- encoded indices, packed write ----
        float4 e0, e1;
        e0.x = (float)codes.c[0]; e0.y = (float)codes.c[1];
        e0.z = (float)codes.c[2]; e0.w = (float)codes.c[3];
        e1.x = (float)codes.c[4]; e1.y = (float)codes.c[5];
        e1.z = (float)codes.c[6]; e1.w = (float)codes.c[7];
        *(float4*)(out_enc + (size_t)iv * QN)     = e0;
        *(float4*)(out_enc + (size_t)iv * QN + 4) = e1;

        // ---- quantized output: reference-exact q rebuilt from codes (frozen) ----
        float4* qo = (float4*)(out_q + (size_t)iv * DN);
        #pragma unroll 1
        for (int d4 = 0; d4 < DN / 4; ++d4) {
            float q0 = 0.f, q1 = 0.f, q2 = 0.f, q3 = 0.f;
            #pragma unroll
            for (int l = 0; l < QN; ++l) {
                const float4 v = *(const float4*)(
                    cb + ((size_t)l * KN + codes.c[l]) * DN + 4 * d4);
                q0 = __fadd_rn(q0, v.x); q1 = __fadd_rn(q1, v.y);
                q2 = __fadd_rn(q2, v.z); q3 = __fadd_rn(q3, v.w);
            }
            float4 o; o.x = q0; o.y = q1; o.z = q2; o.w = q3;
            qo[d4] = o;
        }
    }
}

extern "C" void kernel_launch(void* const* d_in, const int* in_sizes, int n_in,
                              void* d_out, int out_size, void* d_ws, size_t ws_size,
                              hipStream_t stream) {
    const float* x   = (const float*)d_in[0];
    const float* cbp = (const float*)d_in[1];
    const int n = in_sizes[0] / DN;

    float* out_enc = (float*)d_out;                   // [N, Q]
    float* out_q   = (float*)d_out + (size_t)n * QN;  // [N, D]

    // workspace: 1 MiB apackH + 1 MiB apackL (fragment-order fp16) + 32 KiB ||c||^2
    uint32_t* apackH = (uint32_t*)d_ws;
    uint32_t* apackL = (uint32_t*)((char*)d_ws + (size_t)QN * KN * DN * 2);
    float*    cn     = (float*)((char*)d_ws + (size_t)QN * KN * DN * 4);

    rvq_prep_kernel<<<dim3((QN * KN + 255) / 256), dim3(256), 0, stream>>>(
        cbp, apackH, apackL, cn);
    rvq_encode_kernel<<<dim3((n + 63) / 64), dim3(64), 0, stream>>>(
        x, cbp, apackH, apackL, cn, out_enc, out_q, n);
}

// Round 3
// 2417.568 us; speedup vs baseline: 3.0044x; 1.3091x over previous
//
#include <hip/hip_runtime.h>
#include <float.h>
#include <stdint.h>

#define QN 8
#define KN 1024
#define DN 64
// split-fp16 scan error bound ~1.5e-3 (dropped rl*cl + fp32 accum + np-side gap noise);
// margin 4x that
#define MARGIN 6.0e-3f

typedef float    f32x16 __attribute__((ext_vector_type(16)));
typedef _Float16 f16x8  __attribute__((ext_vector_type(8)));

union AB8 { uint4 v; uint32_t u[4]; f16x8 h; };

struct CodeArr { int c[QN]; };

// ===================== FROZEN reference-emulation machinery =====================
__device__ __forceinline__ float np_sumsq64(const float* a) {
    float p[DN];
    #pragma unroll
    for (int t = 0; t < DN; ++t) p[t] = __fmul_rn(a[t], a[t]);
    float l1[32];
    #pragma unroll
    for (int t = 0; t < 32; ++t) l1[t] = __fadd_rn(p[t], p[t + 32]);
    float l2[16];
    #pragma unroll
    for (int t = 0; t < 16; ++t) l2[t] = __fadd_rn(l1[t], l1[t + 16]);
    float l3[8];
    #pragma unroll
    for (int t = 0; t < 8; ++t) l3[t] = __fadd_rn(l2[t], l2[t + 8]);
    float l4[4];
    #pragma unroll
    for (int t = 0; t < 4; ++t) l4[t] = __fadd_rn(l3[t], l3[t + 4]);
    const float l5a = __fadd_rn(l4[0], l4[2]);
    const float l5b = __fadd_rn(l4[1], l4[3]);
    return __fadd_rn(l5a, l5b);
}

// Reference-exact residual rebuild, all 64 dims, J compile-time (static code indexing).
// Per-element op chain identical to the validated ref_res cascade: qd = (((c0+c1)+c2)...),
// rex = x - qd, each op individually rounded.
template<int J>
__device__ __forceinline__ void build_rex(const float* __restrict__ xrow,
                                          const float* __restrict__ cb,
                                          const CodeArr& codes, float rex[DN]) {
    #pragma unroll
    for (int d4 = 0; d4 < DN / 4; ++d4) {
        const float4 xv = *(const float4*)(xrow + 4 * d4);
        float q0 = 0.f, q1 = 0.f, q2 = 0.f, q3 = 0.f;
        #pragma unroll
        for (int l = 0; l < J; ++l) {
            const float4 cv = *(const float4*)(
                cb + ((size_t)l * KN + codes.c[l]) * DN + 4 * d4);
            q0 = __fadd_rn(q0, cv.x); q1 = __fadd_rn(q1, cv.y);
            q2 = __fadd_rn(q2, cv.z); q3 = __fadd_rn(q3, cv.w);
        }
        rex[4*d4+0] = __fsub_rn(xv.x, q0); rex[4*d4+1] = __fsub_rn(xv.y, q1);
        rex[4*d4+2] = __fsub_rn(xv.z, q2); rex[4*d4+3] = __fsub_rn(xv.w, q3);
    }
}

// Frozen rr butterfly tree over the exact residual (identical op sequence).
__device__ __forceinline__ float rr_tree(const float rex[DN]) {
    float l1[32];
    #pragma unroll
    for (int t = 0; t < 32; ++t)
        l1[t] = __fadd_rn(__fmul_rn(rex[t], rex[t]), __fmul_rn(rex[t+32], rex[t+32]));
    float l2[16];
    #pragma unroll
    for (int t = 0; t < 16; ++t) l2[t] = __fadd_rn(l1[t], l1[t + 16]);
    float l3[8];
    #pragma unroll
    for (int t = 0; t < 8; ++t) l3[t] = __fadd_rn(l2[t], l2[t + 8]);
    float l4[4];
    #pragma unroll
    for (int t = 0; t < 4; ++t) l4[t] = __fadd_rn(l3[t], l3[t + 4]);
    return __fadd_rn(__fadd_rn(l4[0], l4[2]), __fadd_rn(l4[1], l4[3]));
}

// Frozen 2-candidate exact rescore. rex computed once (bit-identical values to the
// per-use ref_res recomputation of the validated version). Sequential-FMA cr chains.
template<int J>
__device__ __forceinline__ int rescore2_t(const float* __restrict__ xrow,
                                          const float* __restrict__ cb,
                                          const float* __restrict__ cnj,
                                          const CodeArr& codes, int i1, int i2) {
    float rex[DN];
    build_rex<J>(xrow, cb, codes, rex);
    const float rr = rr_tree(rex);

    const float* cbj = cb + (size_t)J * KN * DN;
    const float* c0p = cbj + (size_t)i1 * DN;
    const float* c1p = cbj + (size_t)i2 * DN;
    float cr0 = 0.f, cr1 = 0.f;
    #pragma unroll
    for (int d4 = 0; d4 < DN / 4; ++d4) {
        const float4 a = *(const float4*)(c0p + 4 * d4);
        const float4 b = *(const float4*)(c1p + 4 * d4);
        cr0 = __fmaf_rn(rex[4*d4+0], a.x, cr0); cr1 = __fmaf_rn(rex[4*d4+0], b.x, cr1);
        cr0 = __fmaf_rn(rex[4*d4+1], a.y, cr0); cr1 = __fmaf_rn(rex[4*d4+1], b.y, cr1);
        cr0 = __fmaf_rn(rex[4*d4+2], a.z, cr0); cr1 = __fmaf_rn(rex[4*d4+2], b.z, cr1);
        cr0 = __fmaf_rn(rex[4*d4+3], a.w, cr0); cr1 = __fmaf_rn(rex[4*d4+3], b.w, cr1);
    }
    const float d2c0 = __fadd_rn(__fsub_rn(rr, __fmul_rn(2.0f, cr0)), cnj[i1]);
    const float d2c1 = __fadd_rn(__fsub_rn(rr, __fmul_rn(2.0f, cr1)), cnj[i2]);

    float bd = d2c0; int bk = i1;
    if (d2c1 < bd || (d2c1 == bd && i2 < bk)) { bd = d2c1; bk = i2; }
    return bk;
}

// Full reference-exact scan, k-unrolled x4 (per-k sequential FMA chain preserved;
// compare fold kept in ascending-k order => exact jnp.argmin tie-break).
template<int J>
__device__ __forceinline__ int full_exact_t(const float* __restrict__ xrow,
                                            const float* __restrict__ cb,
                                            const float* __restrict__ cnj,
                                            const CodeArr& codes) {
    float rex[DN];
    build_rex<J>(xrow, cb, codes, rex);
    const float rr = rr_tree(rex);

    const float* cbj = cb + (size_t)J * KN * DN;
    float bd = FLT_MAX; int bk = 0;
    #pragma unroll 1
    for (int k = 0; k < KN; k += 4) {
        float cr0 = 0.f, cr1 = 0.f, cr2 = 0.f, cr3 = 0.f;
        const float* p0 = cbj + (size_t)(k + 0) * DN;
        const float* p1 = cbj + (size_t)(k + 1) * DN;
        const float* p2 = cbj + (size_t)(k + 2) * DN;
        const float* p3 = cbj + (size_t)(k + 3) * DN;
        #pragma unroll
        for (int d4 = 0; d4 < DN / 4; ++d4) {
            const float4 a = *(const float4*)(p0 + 4 * d4);
            const float4 b = *(const float4*)(p1 + 4 * d4);
            const float4 c = *(const float4*)(p2 + 4 * d4);
            const float4 e = *(const float4*)(p3 + 4 * d4);
            const float r0 = rex[4*d4+0], r1 = rex[4*d4+1];
            const float r2 = rex[4*d4+2], r3 = rex[4*d4+3];
            cr0 = __fmaf_rn(r0, a.x, cr0); cr0 = __fmaf_rn(r1, a.y, cr0);
            cr0 = __fmaf_rn(r2, a.z, cr0); cr0 = __fmaf_rn(r3, a.w, cr0);
            cr1 = __fmaf_rn(r0, b.x, cr1); cr1 = __fmaf_rn(r1, b.y, cr1);
            cr1 = __fmaf_rn(r2, b.z, cr1); cr1 = __fmaf_rn(r3, b.w, cr1);
            cr2 = __fmaf_rn(r0, c.x, cr2); cr2 = __fmaf_rn(r1, c.y, cr2);
            cr2 = __fmaf_rn(r2, c.z, cr2); cr2 = __fmaf_rn(r3, c.w, cr2);
            cr3 = __fmaf_rn(r0, e.x, cr3); cr3 = __fmaf_rn(r1, e.y, cr3);
            cr3 = __fmaf_rn(r2, e.z, cr3); cr3 = __fmaf_rn(r3, e.w, cr3);
        }
        const float d20 = __fadd_rn(__fsub_rn(rr, __fmul_rn(2.0f, cr0)), cnj[k + 0]);
        const float d21 = __fadd_rn(__fsub_rn(rr, __fmul_rn(2.0f, cr1)), cnj[k + 1]);
        const float d22 = __fadd_rn(__fsub_rn(rr, __fmul_rn(2.0f, cr2)), cnj[k + 2]);
        const float d23 = __fadd_rn(__fsub_rn(rr, __fmul_rn(2.0f, cr3)), cnj[k + 3]);
        if (d20 < bd) { bd = d20; bk = k + 0; }
        if (d21 < bd) { bd = d21; bk = k + 1; }
        if (d22 < bd) { bd = d22; bk = k + 2; }
        if (d23 < bd) { bd = d23; bk = k + 3; }
    }
    return bk;
}

// Single cold-path entry; j is a literal at every call site (stage loop is unrolled),
// the switch dispatches to statically-indexed template bodies (no scratch arrays).
__device__ __attribute__((noinline)) int rescue_dispatch(
    int j, int deep, const float* __restrict__ xrow, const float* __restrict__ cb,
    const float* __restrict__ cnj, CodeArr codes, int i1, int i2) {
    switch (j) {
#define RESCUE_CASE(J) case J: return deep ? full_exact_t<J>(xrow, cb, cnj, codes) \
                                           : rescore2_t<J>(xrow, cb, cnj, codes, i1, i2);
        RESCUE_CASE(0) RESCUE_CASE(1) RESCUE_CASE(2) RESCUE_CASE(3)
        RESCUE_CASE(4) RESCUE_CASE(5) RESCUE_CASE(6) RESCUE_CASE(7)
#undef RESCUE_CASE
    }
    return i1;
}
// ===============================================================================

// ---------- Phase A: exact ||c||^2 + split-fp16(-2c) codebook in fragment order ----------
__global__ __launch_bounds__(256) void rvq_prep_kernel(const float* __restrict__ cb,
                                                       uint32_t* __restrict__ apackH,
                                                       uint32_t* __restrict__ apackL,
                                                       float* __restrict__ cn) {
    const int cidx = (int)blockIdx.x * 256 + (int)threadIdx.x;
    if (cidx >= QN * KN) return;
    float row[DN];
    const float4* cp = (const float4*)(cb + (size_t)cidx * DN);
    #pragma unroll
    for (int d4 = 0; d4 < DN / 4; ++d4) {
        const float4 v = cp[d4];
        row[4*d4+0] = v.x; row[4*d4+1] = v.y; row[4*d4+2] = v.z; row[4*d4+3] = v.w;
    }
    cn[cidx] = np_sumsq64(row);                       // frozen exact ||c||^2

    const int j = cidx >> 10, local = cidx & 1023;
    const int c = local >> 5, col = local & 31;
    #pragma unroll
    for (int kk = 0; kk < 4; ++kk) {
        #pragma unroll
        for (int hh = 0; hh < 2; ++hh) {
            AB8 uh, ul;
            #pragma unroll
            for (int e = 0; e < 8; ++e) {
                const float v = -2.0f * row[kk * 16 + hh * 8 + e];   // exact (x2, negate)
                const _Float16 hi = (_Float16)v;
                const float hr = (float)hi;
                const _Float16 lo = (_Float16)__fsub_rn(v, hr);
                uh.h[e] = hi; ul.h[e] = lo;
            }
            const size_t off = (((size_t)(j * 32 + c) * 4 + kk) * 256
                                + (((hh << 5) | col) << 2));
            *(uint4*)(apackH + off) = uh.v;
            *(uint4*)(apackL + off) = ul.v;
        }
    }
}

// med3-based top-3 insert: b3' = med3(s,b2,b3); b2' = med3(s,b1,b2); b1' = min(s,b1).
// Verified identities (b1<=b2<=b3 invariant). Strict < keeps earliest index on ties
// (rescued exactly via the MARGIN trigger when it matters).
#define INSV(sv, ixv, B1v, I1v, B2v, I2v, B3v) do {                          \
    const bool lt1 = (sv) < B1v, lt2 = (sv) < B2v;                           \
    B3v = __builtin_amdgcn_fmed3f((sv), B2v, B3v);                           \
    B2v = __builtin_amdgcn_fmed3f((sv), B1v, B2v);                           \
    I2v = lt1 ? I1v : (lt2 ? (ixv) : I2v);                                   \
    B1v = fminf((sv), B1v);                                                  \
    I1v = lt1 ? (ixv) : I1v;                                                 \
} while (0)

// ---------- Main: barrier-free split-fp16 MFMA scan, L2-direct fragments ----------
// 256-thread blocks = 4 INDEPENDENT waves (no barriers, no shared LDS) -> ~16 waves/CU
// residency. Each wave covers 64 vectors (2 column groups sharing the A operand).
__global__ __launch_bounds__(256, 4) void rvq_encode_kernel(
    const float* __restrict__ x, const float* __restrict__ cb,
    const uint32_t* __restrict__ apackH, const uint32_t* __restrict__ apackL,
    const float* __restrict__ cnref,
    float* __restrict__ out_enc, float* __restrict__ out_q, int n) {
    const int tid  = (int)threadIdx.x;
    const int lane = tid & 63;
    const int h    = lane >> 5;
    const int iv   = (int)blockIdx.x * 256 + tid;
    const int ivs  = iv < n ? iv : (n - 1);
    const float* xrow = x + (size_t)ivs * DN;

    CodeArr codes;

    #pragma unroll
    for (int j = 0; j < QN; ++j) {
        // ---- exact residual rebuild + split-fp16 pack + B-fragment build ----
        f16x8 bh0[4], bh1[4], bl0[4], bl1[4];
        #pragma unroll
        for (int kk = 0; kk < 4; ++kk) {
            float rex[16];
            #pragma unroll
            for (int d4 = 0; d4 < 4; ++d4) {
                const float4 xv = *(const float4*)(xrow + kk * 16 + 4 * d4);
                float q0 = 0.f, q1 = 0.f, q2 = 0.f, q3 = 0.f;
                #pragma unroll
                for (int l = 0; l < j; ++l) {     // j compile-time: fully unrolled
                    const float4 cv = *(const float4*)(
                        cb + ((size_t)l * KN + codes.c[l]) * DN + kk * 16 + 4 * d4);
                    q0 = __fadd_rn(q0, cv.x); q1 = __fadd_rn(q1, cv.y);
                    q2 = __fadd_rn(q2, cv.z); q3 = __fadd_rn(q3, cv.w);
                }
                rex[4*d4+0] = __fsub_rn(xv.x, q0); rex[4*d4+1] = __fsub_rn(xv.y, q1);
                rex[4*d4+2] = __fsub_rn(xv.z, q2); rex[4*d4+3] = __fsub_rn(xv.w, q3);
            }
            uint32_t rh[8], rl[8];
            #pragma unroll
            for (int m = 0; m < 8; ++m) {
                const float a = rex[2*m], b = rex[2*m+1];
                const _Float16 ah16 = (_Float16)a; const float ar = (float)ah16;
                const _Float16 al16 = (_Float16)__fsub_rn(a, ar);
                const _Float16 bh16 = (_Float16)b; const float br = (float)bh16;
                const _Float16 bl16 = (_Float16)__fsub_rn(b, br);
                rh[m] = (uint32_t)__builtin_bit_cast(uint16_t, ah16)
                      | ((uint32_t)__builtin_bit_cast(uint16_t, bh16) << 16);
                rl[m] = (uint32_t)__builtin_bit_cast(uint16_t, al16)
                      | ((uint32_t)__builtin_bit_cast(uint16_t, bl16) << 16);
            }
            AB8 t0, t1, s0, s1;
            #pragma unroll
            for (int q = 0; q < 4; ++q) {
                const uint32_t lo  = rh[q],     hi  = rh[4 + q];
                const uint32_t plo = (uint32_t)__shfl_xor((int)lo, 32, 64);
                const uint32_t phi = (uint32_t)__shfl_xor((int)hi, 32, 64);
                t0.u[q] = h ? phi : lo;
                t1.u[q] = h ? hi  : plo;
                const uint32_t llo = rl[q],     lhi = rl[4 + q];
                const uint32_t qlo = (uint32_t)__shfl_xor((int)llo, 32, 64);
                const uint32_t qhi = (uint32_t)__shfl_xor((int)lhi, 32, 64);
                s0.u[q] = h ? qhi : llo;
                s1.u[q] = h ? lhi : qlo;
            }
            bh0[kk] = t0.h; bh1[kk] = t1.h; bl0[kk] = s0.h; bl1[kk] = s1.h;
        }

        float b1g0 = FLT_MAX, b2g0 = FLT_MAX, b3g0 = FLT_MAX; int i1g0 = 0, i2g0 = 0;
        float b1g1 = FLT_MAX, b2g1 = FLT_MAX, b3g1 = FLT_MAX; int i1g1 = 0, i2g1 = 0;

        const uint32_t* aH  = apackH + (size_t)j * 32768;
        const uint32_t* aL  = apackL + (size_t)j * 32768;
        const float*    cnj = cnref + (size_t)j * KN;

        #pragma unroll 1
        for (int ch = 0; ch < 32; ++ch) {
            f32x16 acc0;
            #pragma unroll
            for (int q = 0; q < 4; ++q) {
                const float4 t = *(const float4*)(cnj + ch * 32 + q * 8 + h * 4);
                acc0[4*q+0] = t.x; acc0[4*q+1] = t.y; acc0[4*q+2] = t.z; acc0[4*q+3] = t.w;
            }
            f32x16 acc1 = acc0;
            #pragma unroll
            for (int kk = 0; kk < 4; ++kk) {
                AB8 ah_, al_;
                ah_.v = *(const uint4*)(aH + (size_t)(ch * 4 + kk) * 256 + lane * 4);
                al_.v = *(const uint4*)(aL + (size_t)(ch * 4 + kk) * 256 + lane * 4);
                acc0 = __builtin_amdgcn_mfma_f32_32x32x16_f16(ah_.h, bh0[kk], acc0, 0, 0, 0);
                acc1 = __builtin_amdgcn_mfma_f32_32x32x16_f16(ah_.h, bh1[kk], acc1, 0, 0, 0);
                acc0 = __builtin_amdgcn_mfma_f32_32x32x16_f16(al_.h, bh0[kk], acc0, 0, 0, 0);
                acc1 = __builtin_amdgcn_mfma_f32_32x32x16_f16(al_.h, bh1[kk], acc1, 0, 0, 0);
                acc0 = __builtin_amdgcn_mfma_f32_32x32x16_f16(ah_.h, bl0[kk], acc0, 0, 0, 0);
                acc1 = __builtin_amdgcn_mfma_f32_32x32x16_f16(ah_.h, bl1[kk], acc1, 0, 0, 0);
            }
            const int ibase = ch * 32 + 4 * h;
            #pragma unroll
            for (int q = 0; q < 16; ++q) {
                const int ix = ibase + (q & 3) + 8 * (q >> 2);
                { const float s = acc0[q]; INSV(s, ix, b1g0, i1g0, b2g0, i2g0, b3g0); }
                { const float s = acc1[q]; INSV(s, ix, b1g1, i1g1, b2g1, i2g1, b3g1); }
            }
        }

        // ---- merge K-half partial lists (lanes l <-> l^32); pb3 can never reach
        // the I2 slot (pb3 >= partner's b2 >= merged b2), dummy index safe ----
        {
            const float pb1 = __shfl_xor(b1g0, 32, 64); const int pi1 = __shfl_xor(i1g0, 32, 64);
            const float pb2 = __shfl_xor(b2g0, 32, 64); const int pi2 = __shfl_xor(i2g0, 32, 64);
            const float pb3 = __shfl_xor(b3g0, 32, 64);
            INSV(pb1, pi1, b1g0, i1g0, b2g0, i2g0, b3g0);
            INSV(pb2, pi2, b1g0, i1g0, b2g0, i2g0, b3g0);
            INSV(pb3, 0,   b1g0, i1g0, b2g0, i2g0, b3g0);
        }
        {
            const float pb1 = __shfl_xor(b1g1, 32, 64); const int pi1 = __shfl_xor(i1g1, 32, 64);
            const float pb2 = __shfl_xor(b2g1, 32, 64); const int pi2 = __shfl_xor(i2g1, 32, 64);
            const float pb3 = __shfl_xor(b3g1, 32, 64);
            INSV(pb1, pi1, b1g1, i1g1, b2g1, i2g1, b3g1);
            INSV(pb2, pi2, b1g1, i1g1, b2g1, i2g1, b3g1);
            INSV(pb3, 0,   b1g1, i1g1, b2g1, i2g1, b3g1);
        }
        const float sb1 = h ? b1g1 : b1g0;
        const float sb2 = h ? b2g1 : b2g0;
        const float sb3 = h ? b3g1 : b3g0;
        const int   si1 = h ? i1g1 : i1g0;
        const int   si2 = h ? i2g1 : i2g0;

        int chosen = si1;
        if (__builtin_expect(sb2 - sb1 < MARGIN, 0)) {
            const int deep = (sb3 - sb1 < MARGIN) ? 1 : 0;
            chosen = rescue_dispatch(j, deep, xrow, cb, cnj, codes, si1, si2);
        }
        codes.c[j] = chosen;
    }

    if (iv < n) {
        // ---- encoded indices, packed write ----
        float4 e0, e1;
        e0.x = (float)codes.c[0]; e0.y = (float)codes.c[1];
        e0.z = (float)codes.c[2]; e0.w = (float)codes.c[3];
        e1.x = (float)codes.c[4]; e1.y = (float)codes.c[5];
        e1.z = (float)codes.c[6]; e1.w = (float)codes.c[7];
        *(float4*)(out_enc + (size_t)iv * QN)     = e0;
        *(float4*)(out_enc + (size_t)iv * QN + 4) = e1;

        // ---- quantized output: reference-exact q rebuilt from codes (frozen) ----
        float4* qo = (float4*)(out_q + (size_t)iv * DN);
        #pragma unroll 1
        for (int d4 = 0; d4 < DN / 4; ++d4) {
            float q0 = 0.f, q1 = 0.f, q2 = 0.f, q3 = 0.f;
            #pragma unroll
            for (int l = 0; l < QN; ++l) {
                const float4 v = *(const float4*)(
                    cb + ((size_t)l * KN + codes.c[l]) * DN + 4 * d4);
                q0 = __fadd_rn(q0, v.x); q1 = __fadd_rn(q1, v.y);
                q2 = __fadd_rn(q2, v.z); q3 = __fadd_rn(q3, v.w);
            }
            float4 o; o.x = q0; o.y = q1; o.z = q2; o.w = q3;
            qo[d4] = o;
        }
    }
}

extern "C" void kernel_launch(void* const* d_in, const int* in_sizes, int n_in,
                              void* d_out, int out_size, void* d_ws, size_t ws_size,
                              hipStream_t stream) {
    const float* x   = (const float*)d_in[0];
    const float* cbp = (const float*)d_in[1];
    const int n = in_sizes[0] / DN;

    float* out_enc = (float*)d_out;                   // [N, Q]
    float* out_q   = (float*)d_out + (size_t)n * QN;  // [N, D]

    // workspace: 1 MiB apackH + 1 MiB apackL (fragment-order fp16) + 32 KiB ||c||^2
    uint32_t* apackH = (uint32_t*)d_ws;
    uint32_t* apackL = (uint32_t*)((char*)d_ws + (size_t)QN * KN * DN * 2);
    float*    cn     = (float*)((char*)d_ws + (size_t)QN * KN * DN * 4);

    rvq_prep_kernel<<<dim3((QN * KN + 255) / 256), dim3(256), 0, stream>>>(
        cbp, apackH, apackL, cn);
    rvq_encode_kernel<<<dim3((n + 255) / 256), dim3(256), 0, stream>>>(
        x, cbp, apackH, apackL, cn, out_enc, out_q, n);
}